// Round 5
// baseline (364.721 us; speedup 1.0000x reference)
//
#include <hip/hip_runtime.h>

#define BB 64
#define PP 8732
#define OO 32
#define CC 81
#define NEGPOS 3
#define NSL_A 18                   // per-prior part: 18*512 = 9216 >= 8732
#define NCH_B 32                   // per-object chunks: 32*273 = 8736 >= 8732
#define CHB 273
#define NCH_CE 69                  // ce chunks per batch: 69*128 = 8832 >= 8732

// ---------------- workspace layout (poison-proof: every word written before read) ----
#define WS_POVFP  0                              // u64 povfp[B*PP]  (iou_bits<<32 | obj)
#define WS_BESTP  (WS_POVFP + BB*PP*8)           // u64 bestp[B*NCH_B*OO]
#define WS_CENEG  (WS_BESTP + BB*NCH_B*OO*8)     // float ce_neg[B*PP]
#define WS_CEPOS  (WS_CENEG + BB*PP*4)           // float cepos[B*NCH_CE]
#define WS_LSUMB  (WS_CEPOS + BB*NCH_CE*4)       // float lsum_bc[B*NCH_CE]
#define WS_NPOSB  (WS_LSUMB + BB*NCH_CE*4)       // int   npos_bc[B*NCH_CE]
#define WS_HARDB  (WS_NPOSB + BB*NCH_CE*4)       // float hard_b[B]
#define WS_DONE   (WS_HARDB + BB*4)              // int   done

// ---------------- kernel 1: fused geometry (per-prior argmax  +  per-object argmax) ---
// grid (NSL_A + NCH_B, B) x 512. blockIdx.x < NSL_A -> per-prior; else per-object chunk.
__global__ __launch_bounds__(512) void match_geom(
    const float* __restrict__ boxes, const float* __restrict__ priors,
    unsigned long long* __restrict__ povfp, unsigned long long* __restrict__ bestp,
    int* __restrict__ done)
{
    const int b = blockIdx.y, gx = blockIdx.x, tid = threadIdx.x;
    __shared__ float sbx[OO * 4];
    __shared__ unsigned long long sred[8 * OO];
    if (tid < OO * 4) sbx[tid] = boxes[b * OO * 4 + tid];
    if (gx == 0 && b == 0 && tid == 0) *done = 0;   // ticket for topk's fused finalize
    __syncthreads();

    if (gx < NSL_A) {
        // ---- per-prior best object: 1 prior/thread, running max in registers ----
        const int p = gx * 512 + tid;
        if (p >= PP) return;
        float4 pr = ((const float4*)priors)[p];
        float plx = pr.x - pr.z * 0.5f, ply = pr.y - pr.w * 0.5f;
        float phx = pr.x + pr.z * 0.5f, phy = pr.y + pr.w * 0.5f;
        float parea = pr.z * pr.w;
        float bestv = -1.0f; int besto = 0;
#pragma unroll
        for (int o = 0; o < OO; ++o) {
            float b0 = sbx[o*4+0], b1 = sbx[o*4+1], b2 = sbx[o*4+2], b3 = sbx[o*4+3];
            float lox = fmaxf(b0, plx), loy = fmaxf(b1, ply);
            float hix = fminf(b2, phx), hiy = fminf(b3, phy);
            float inter = fmaxf(hix - lox, 0.0f) * fmaxf(hiy - loy, 0.0f);
            float iou = inter / ((b2 - b0) * (b3 - b1) + parea - inter);
            if (iou > bestv) { bestv = iou; besto = o; }   // strict >: np first-max
        }
        povfp[b * PP + p] = ((unsigned long long)__float_as_uint(bestv) << 32) | (unsigned)besto;
    } else {
        // ---- per-object best prior over one 273-prior chunk ----
        const int ch = gx - NSL_A;
        const int o = tid & 31, sub = tid >> 5;            // sub 0..15
        const float b0 = sbx[o*4+0], b1 = sbx[o*4+1], b2 = sbx[o*4+2], b3 = sbx[o*4+3];
        const float barea = (b2 - b0) * (b3 - b1);
        const int base = ch * CHB;
        unsigned long long best = 0ull;
        for (int i = sub; i < CHB; i += 16) {
            int p = base + i;
            if (p >= PP) break;
            float4 pr = ((const float4*)priors)[p];
            float plx = pr.x - pr.z * 0.5f, ply = pr.y - pr.w * 0.5f;
            float phx = pr.x + pr.z * 0.5f, phy = pr.y + pr.w * 0.5f;
            float parea = pr.z * pr.w;
            float lox = fmaxf(b0, plx), loy = fmaxf(b1, ply);
            float hix = fminf(b2, phx), hiy = fminf(b3, phy);
            float inter = fmaxf(hix - lox, 0.0f) * fmaxf(hiy - loy, 0.0f);
            float iou = inter / (barea + parea - inter);
            unsigned long long enc =
                ((unsigned long long)__float_as_uint(iou) << 32) | (unsigned)(~(unsigned)p);
            best = (enc > best) ? enc : best;              // max iou, tie -> min p
        }
        unsigned long long w = __shfl_down(best, 32, 64);  // lanes l / l+32 share object
        best = (w > best) ? w : best;
        const int wid = tid >> 6, lane = tid & 63;
        if (lane < 32) sred[wid * OO + o] = best;
        __syncthreads();
        if (tid < OO) {
            unsigned long long m = 0ull;
#pragma unroll
            for (int wv = 0; wv < 8; ++wv) {
                unsigned long long v = sred[wv * OO + tid];
                m = (v > m) ? v : m;
            }
            bestp[(b * NCH_B + ch) * OO + tid] = m;
        }
    }
}

// ---------------- kernel 2: fused match_b + cross entropy ----------------
// grid (NCH_CE, B) x 128. Stages scores to LDS (coalesced float4); label/override/
// loc-loss VALU work rides in the HBM shadow. No lab intermediate.
__global__ __launch_bounds__(128) void ce_match(
    const float* __restrict__ scores, const float* __restrict__ pred_locs,
    const float* __restrict__ boxes, const int* __restrict__ labels,
    const float* __restrict__ priors,
    const unsigned long long* __restrict__ povfp,
    const unsigned long long* __restrict__ bestp,
    float* __restrict__ ce_neg, float* __restrict__ cepos,
    float* __restrict__ lsum_bc, int* __restrict__ npos_bc)
{
    __shared__ float ss[128 * CC];   // 41472 B
    __shared__ float sbx[OO * 4];
    __shared__ int   slab[OO];
    __shared__ int   spfo[OO];
    __shared__ signed char sovr[128];
    __shared__ float srf[2], srl[2];
    __shared__ int   sri[2];

    const int b = blockIdx.y, ch = blockIdx.x, tid = threadIdx.x;
    const int base = ch * 128;
    const int nval = (PP - base < 128) ? (PP - base) : 128;   // 128 or 28 (tail)

    // stage scores (coalesced float4; nval*CC divisible by 4)
    const float4* __restrict__ src =
        (const float4*)(scores + ((long long)b * PP + base) * CC);
    float4* dst = (float4*)ss;
    const int n4 = (nval * CC) / 4;
    for (int i = tid; i < n4; i += 128) dst[i] = src[i];

    if (tid < OO * 4) sbx[tid] = boxes[b * OO * 4 + tid];
    if (tid < OO)     slab[tid] = labels[b * OO + tid];
    if (tid < OO) {    // reduce chunk-partials -> prior_for_object (L2-hot, 8 KB/batch)
        unsigned long long m = 0ull;
        for (int c = 0; c < NCH_B; ++c) {
            unsigned long long v = bestp[(b * NCH_B + c) * OO + tid];
            m = (v > m) ? v : m;
        }
        spfo[tid] = (int)(~(unsigned)(m & 0xFFFFFFFFull));
    }
    sovr[tid] = -1;
    __syncthreads();
    if (tid == 0) {    // ascending o => last-write-wins (numpy scatter semantics)
        for (int o = 0; o < OO; ++o) {
            int p = spfo[o] - base;
            if (p >= 0 && p < 128) sovr[p] = (signed char)o;
        }
    }
    __syncthreads();

    float pos = 0.0f, lsum = 0.0f; int lpos = 0;
    if (tid < nval) {
        const int p = base + tid;
        const float* v = ss + tid * CC;   // stride 81: 2-way bank aliasing (free)
        float m = v[0];
#pragma unroll
        for (int c = 1; c < CC; ++c) m = fmaxf(m, v[c]);
        float sum = 0.0f;
#pragma unroll
        for (int c = 0; c < CC; ++c) sum += __expf(v[c] - m);
        float lse = m + __logf(sum);

        unsigned long long pv = povfp[b * PP + p];
        int o = (int)(pv & 0xFFu);
        float ov = __uint_as_float((unsigned)(pv >> 32));
        int ovr = sovr[tid];
        if (ovr >= 0) { o = ovr; ov = 1.0f; }
        int l = (ov < 0.5f) ? 0 : slab[o];
        float ce = lse - v[l];
        ce_neg[b * PP + p] = (l != 0) ? 0.0f : ce;
        if (l != 0) {
            pos = ce; lpos = 1;
            float b0 = sbx[o*4+0], b1 = sbx[o*4+1], b2 = sbx[o*4+2], b3 = sbx[o*4+3];
            float4 pr = ((const float4*)priors)[p];
            float gx = ((b0 + b2) * 0.5f - pr.x) / (pr.z * 0.1f);
            float gy = ((b1 + b3) * 0.5f - pr.y) / (pr.w * 0.1f);
            float gw = logf((b2 - b0) / pr.z) * 5.0f;
            float gh = logf((b3 - b1) / pr.w) * 5.0f;
            float4 pl = ((const float4*)pred_locs)[b * PP + p];
            lsum = fabsf(pl.x - gx) + fabsf(pl.y - gy) + fabsf(pl.z - gw) + fabsf(pl.w - gh);
        }
    }
    for (int off = 32; off > 0; off >>= 1) {
        pos  += __shfl_down(pos, off, 64);
        lsum += __shfl_down(lsum, off, 64);
        lpos += __shfl_down(lpos, off, 64);
    }
    if ((tid & 63) == 0) { int w = tid >> 6; srf[w] = pos; srl[w] = lsum; sri[w] = lpos; }
    __syncthreads();
    if (tid == 0) {
        cepos[b * NCH_CE + ch]   = srf[0] + srf[1];
        lsum_bc[b * NCH_CE + ch] = srl[0] + srl[1];
        npos_bc[b * NCH_CE + ch] = sri[0] + sri[1];
    }
}

// ---------------- kernel 3: per-batch exact top-K radix select + fused finalize -------
// grid B x 512. Parallel suffix-scan bin selection; last block writes out[0].
__global__ __launch_bounds__(512) void topk_kernel(
    const float* __restrict__ ce_neg, const int* __restrict__ npos_bc,
    const float* __restrict__ cepos, const float* __restrict__ lsum_bc,
    float* __restrict__ hard_b, int* __restrict__ done, float* __restrict__ out)
{
    __shared__ float sv[PP];          // 34928 B
    __shared__ int hist[256 * 16];    // 16-way slot-split histogram (16 KB)
    __shared__ int ssum[256];
    __shared__ unsigned sel[2];
    __shared__ float sr[8];
    __shared__ int sK;
    const int b = blockIdx.x, tid = threadIdx.x;
    for (int p = tid; p < PP; p += 512) sv[p] = ce_neg[b * PP + p];
    if (tid == 0) {
        int n = 0;
        for (int c = 0; c < NCH_CE; ++c) n += npos_bc[b * NCH_CE + c];
        int k = NEGPOS * n;
        sK = (k > PP) ? PP : k;
    }
    __syncthreads();
    const int K = sK;

    float hard = 0.0f;
    if (K > 0) {
        unsigned prefix = 0, mask = 0;
        unsigned remaining = (unsigned)K;
        for (int pass = 0; pass < 4; ++pass) {
            const int shift = 24 - 8 * pass;
            for (int i = tid; i < 256 * 16; i += 512) hist[i] = 0;
            __syncthreads();
            for (int p = tid; p < PP; p += 512) {
                unsigned u = __float_as_uint(sv[p]);   // all ce >= 0: bits monotone
                if ((u & mask) == prefix)
                    atomicAdd(&hist[(((u >> shift) & 255) << 4) | (tid & 15)], 1);
            }
            __syncthreads();
            if (tid < 256) {   // thread i compacts bin i
                int s = 0;
#pragma unroll
                for (int w = 0; w < 16; ++w) s += hist[(tid << 4) | w];
                ssum[tid] = s;
            }
            __syncthreads();
            // parallel suffix sum (Hillis-Steele): ssum[i] = sum_{j>=i} count[j]
            for (int off = 1; off < 256; off <<= 1) {
                int v = 0;
                if (tid < 256) v = (tid + off < 256) ? ssum[tid + off] : 0;
                __syncthreads();
                if (tid < 256) ssum[tid] += v;
                __syncthreads();
            }
            if (tid < 256 && (unsigned)ssum[tid] >= remaining &&
                (tid == 255 || (unsigned)ssum[tid + 1] < remaining)) {
                sel[0] = (unsigned)tid;
                sel[1] = remaining - ((tid == 255) ? 0u : (unsigned)ssum[tid + 1]);
            }
            __syncthreads();
            prefix |= sel[0] << shift;
            mask |= 0xFFu << shift;
            remaining = sel[1];
            __syncthreads();
        }
        // prefix = bits of K-th largest; remaining = # cutoff-valued elems inside top-K
        float sgt = 0.0f;
        for (int p = tid; p < PP; p += 512) {
            unsigned u = __float_as_uint(sv[p]);
            if (u > prefix) sgt += sv[p];
        }
        for (int off = 32; off > 0; off >>= 1) sgt += __shfl_down(sgt, off, 64);
        if ((tid & 63) == 0) sr[tid >> 6] = sgt;
        __syncthreads();
        if (tid == 0) {
            hard = 0.0f;
#pragma unroll
            for (int w = 0; w < 8; ++w) hard += sr[w];
            hard += __uint_as_float(prefix) * (float)remaining;
        }
    }
    __shared__ int sticket;
    if (tid == 0) {
        hard_b[b] = hard;
        __threadfence();                 // device-scope: flush before taking ticket
        sticket = atomicAdd(done, 1);
    }
    __syncthreads();
    if (sticket != BB - 1) return;

    // ---- fused finalize (last block only) ----
    float cpos = 0.0f, labs = 0.0f, chard = 0.0f; int n = 0;
    for (int i = tid; i < BB * NCH_CE; i += 512) {
        cpos += cepos[i];                 // prior-kernel outputs: visible at launch edge
        labs += lsum_bc[i];
        n    += npos_bc[i];
    }
    if (tid < BB) chard = atomicAdd(&hard_b[tid], 0.0f);   // atomic load: XCD-coherent
    for (int off = 32; off > 0; off >>= 1) {
        cpos  += __shfl_down(cpos, off, 64);
        labs  += __shfl_down(labs, off, 64);
        chard += __shfl_down(chard, off, 64);
        n     += __shfl_down(n, off, 64);
    }
    __shared__ float f0[8], f1[8], f2[8];
    __shared__ int i3[8];
    if ((tid & 63) == 0) { int w = tid >> 6; f0[w] = cpos; f1[w] = labs; f2[w] = chard; i3[w] = n; }
    __syncthreads();
    if (tid == 0) {
        float a = 0.0f, bs = 0.0f, c = 0.0f; int nt = 0;
#pragma unroll
        for (int w = 0; w < 8; ++w) { a += f0[w]; bs += f1[w]; c += f2[w]; nt += i3[w]; }
        float nf = (float)nt;
        out[0] = (c + a) / nf + bs / (nf * 4.0f);
    }
}

extern "C" void kernel_launch(void* const* d_in, const int* in_sizes, int n_in,
                              void* d_out, int out_size, void* d_ws, size_t ws_size,
                              hipStream_t stream) {
    const float* pred_locs   = (const float*)d_in[0];   // [B,P,4]
    const float* pred_scores = (const float*)d_in[1];   // [B,P,C]
    const float* boxes       = (const float*)d_in[2];   // [B,O,4]
    const int*   labels      = (const int*)d_in[3];     // [B,O]
    const float* priors      = (const float*)d_in[4];   // [P,4] cxcywh
    float* out = (float*)d_out;

    char* ws = (char*)d_ws;
    unsigned long long* povfp = (unsigned long long*)(ws + WS_POVFP);
    unsigned long long* bestp = (unsigned long long*)(ws + WS_BESTP);
    float* ce_neg  = (float*)(ws + WS_CENEG);
    float* cepos   = (float*)(ws + WS_CEPOS);
    float* lsum_bc = (float*)(ws + WS_LSUMB);
    int*   nposbc  = (int*)(ws + WS_NPOSB);
    float* hard_b  = (float*)(ws + WS_HARDB);
    int*   done    = (int*)(ws + WS_DONE);

    match_geom<<<dim3(NSL_A + NCH_B, BB), 512, 0, stream>>>(boxes, priors, povfp, bestp, done);
    ce_match<<<dim3(NCH_CE, BB), 128, 0, stream>>>(pred_scores, pred_locs, boxes, labels,
                                                   priors, povfp, bestp,
                                                   ce_neg, cepos, lsum_bc, nposbc);
    topk_kernel<<<BB, 512, 0, stream>>>(ce_neg, nposbc, cepos, lsum_bc, hard_b, done, out);
}

// Round 6
// 321.353 us; speedup vs baseline: 1.1350x; 1.1350x over previous
//
#include <hip/hip_runtime.h>

#define BB 64
#define PP 8732
#define OO 32
#define CC 81
#define NEGPOS 3
#define NSL_A 18                   // per-prior part: 18*512 = 9216 >= 8732
#define NCH_B 32                   // per-object chunks: 32*273 = 8736 >= 8732
#define CHB 273
#define NSL_C 8                    // match_b slices: 8*1092 = 8736 >= 8732
#define SLC 1092
#define NCE 8732                   // ce blocks: 64 priors each, 8732*64 = B*PP exactly

// ---------------- workspace layout (poison-proof: every word written before read) ----
#define WS_POVF   0                              // f32 povf[B*PP]  best iou per prior
#define WS_POVO   (WS_POVF  + BB*PP*4)           // u8  povo[B*PP]  best obj per prior
#define WS_BESTP  (WS_POVO  + BB*PP)             // u64 bestp[B*NCH_B*OO]
#define WS_LAB    (WS_BESTP + BB*NCH_B*OO*8)     // i8  lab[B*PP]
#define WS_CENEG  (WS_LAB   + BB*PP)             // f32 ce_neg[B*PP]
#define WS_CEPOS  (WS_CENEG + BB*PP*4)           // f32 cepos[NCE]
#define WS_LSUMB  (WS_CEPOS + NCE*4)             // f32 lsum_bs[B*NSL_C]
#define WS_NPOSB  (WS_LSUMB + BB*NSL_C*4)        // i32 npos_bs[B*NSL_C]
#define WS_HARDB  (WS_NPOSB + BB*NSL_C*4)        // f32 hard_b[B]
#define WS_DONE   (WS_HARDB + BB*4)              // int done

// ---------------- kernel 1: fused geometry (per-prior argmax + per-object argmax) ----
// grid (NSL_A + NCH_B, B) x 512. blockIdx.x < NSL_A -> per-prior; else per-object chunk.
__global__ __launch_bounds__(512) void match_geom(
    const float* __restrict__ boxes, const float* __restrict__ priors,
    float* __restrict__ povf, unsigned char* __restrict__ povo,
    unsigned long long* __restrict__ bestp, int* __restrict__ done)
{
    const int b = blockIdx.y, gx = blockIdx.x, tid = threadIdx.x;
    __shared__ float sbx[OO * 4];
    __shared__ unsigned long long sred[8 * OO];
    if (tid < OO * 4) sbx[tid] = boxes[b * OO * 4 + tid];
    if (gx == 0 && b == 0 && tid == 0) *done = 0;   // ticket for topk's fused finalize
    __syncthreads();

    if (gx < NSL_A) {
        const int p = gx * 512 + tid;
        if (p >= PP) return;
        float4 pr = ((const float4*)priors)[p];
        float plx = pr.x - pr.z * 0.5f, ply = pr.y - pr.w * 0.5f;
        float phx = pr.x + pr.z * 0.5f, phy = pr.y + pr.w * 0.5f;
        float parea = pr.z * pr.w;
        float bestv = -1.0f; int besto = 0;
#pragma unroll
        for (int o = 0; o < OO; ++o) {
            float b0 = sbx[o*4+0], b1 = sbx[o*4+1], b2 = sbx[o*4+2], b3 = sbx[o*4+3];
            float lox = fmaxf(b0, plx), loy = fmaxf(b1, ply);
            float hix = fminf(b2, phx), hiy = fminf(b3, phy);
            float inter = fmaxf(hix - lox, 0.0f) * fmaxf(hiy - loy, 0.0f);
            float iou = inter / ((b2 - b0) * (b3 - b1) + parea - inter);
            if (iou > bestv) { bestv = iou; besto = o; }   // strict >: np first-max
        }
        povf[b * PP + p] = bestv;
        povo[b * PP + p] = (unsigned char)besto;
    } else {
        const int ch = gx - NSL_A;
        const int o = tid & 31, sub = tid >> 5;            // sub 0..15
        const float b0 = sbx[o*4+0], b1 = sbx[o*4+1], b2 = sbx[o*4+2], b3 = sbx[o*4+3];
        const float barea = (b2 - b0) * (b3 - b1);
        const int base = ch * CHB;
        unsigned long long best = 0ull;
        for (int i = sub; i < CHB; i += 16) {
            int p = base + i;
            if (p >= PP) break;
            float4 pr = ((const float4*)priors)[p];
            float plx = pr.x - pr.z * 0.5f, ply = pr.y - pr.w * 0.5f;
            float phx = pr.x + pr.z * 0.5f, phy = pr.y + pr.w * 0.5f;
            float parea = pr.z * pr.w;
            float lox = fmaxf(b0, plx), loy = fmaxf(b1, ply);
            float hix = fminf(b2, phx), hiy = fminf(b3, phy);
            float inter = fmaxf(hix - lox, 0.0f) * fmaxf(hiy - loy, 0.0f);
            float iou = inter / (barea + parea - inter);
            unsigned long long enc =
                ((unsigned long long)__float_as_uint(iou) << 32) | (unsigned)(~(unsigned)p);
            best = (enc > best) ? enc : best;              // max iou, tie -> min p
        }
        unsigned long long w = __shfl_down(best, 32, 64);  // lanes l / l+32 share object
        best = (w > best) ? w : best;
        const int wid = tid >> 6, lane = tid & 63;
        if (lane < 32) sred[wid * OO + o] = best;
        __syncthreads();
        if (tid < OO) {
            unsigned long long m = 0ull;
#pragma unroll
            for (int wv = 0; wv < 8; ++wv) {
                unsigned long long v = sred[wv * OO + tid];
                m = (v > m) ? v : m;
            }
            bestp[(b * NCH_B + ch) * OO + tid] = m;
        }
    }
}

// ---------------- kernel 2: overrides + labels + loc loss ----------------
// grid (8,B) x 256. LDS override table; writes 1-byte labels.
__global__ __launch_bounds__(256) void match_b(
    const float* __restrict__ pred_locs, const float* __restrict__ boxes,
    const int* __restrict__ labels, const float* __restrict__ priors,
    const float* __restrict__ povf, const unsigned char* __restrict__ povo,
    const unsigned long long* __restrict__ bestp,
    signed char* __restrict__ lab_out, int* __restrict__ npos_bs,
    float* __restrict__ lsum_bs)
{
    const int b = blockIdx.y, sl = blockIdx.x, tid = threadIdx.x;
    const int base = sl * SLC;
    __shared__ float sbx[OO * 4];
    __shared__ int   slab[OO];
    __shared__ int   spfo[OO];
    __shared__ signed char sovr[SLC];
    __shared__ float sredf[4];
    __shared__ int   sredi[4];

    if (tid < OO * 4) sbx[tid] = boxes[b * OO * 4 + tid];
    if (tid < OO)     slab[tid] = labels[b * OO + tid];
    if (tid < OO) {   // reduce the 32 chunk-partials for this object (L2-hot)
        unsigned long long m = 0ull;
        for (int c = 0; c < NCH_B; ++c) {
            unsigned long long v = bestp[(b * NCH_B + c) * OO + tid];
            m = (v > m) ? v : m;
        }
        spfo[tid] = (int)(~(unsigned)(m & 0xFFFFFFFFull));
    }
    for (int i = tid; i < SLC; i += 256) sovr[i] = -1;
    __syncthreads();
    if (tid == 0) {   // ascending o => last-write-wins (numpy scatter semantics)
        for (int o = 0; o < OO; ++o) {
            int p = spfo[o] - base;
            if (p >= 0 && p < SLC) sovr[p] = (signed char)o;
        }
    }
    __syncthreads();

    float lsum = 0.0f; int lpos = 0;
    for (int i = tid; i < SLC; i += 256) {
        int p = base + i;
        if (p >= PP) break;
        int o = (int)povo[b * PP + p];
        float ov = povf[b * PP + p];
        int ovr = sovr[i];
        if (ovr >= 0) { o = ovr; ov = 1.0f; }
        int l = (ov < 0.5f) ? 0 : slab[o];
        lab_out[b * PP + p] = (signed char)l;
        if (l != 0) {
            lpos++;
            float b0 = sbx[o*4+0], b1 = sbx[o*4+1], b2 = sbx[o*4+2], b3 = sbx[o*4+3];
            float4 pr = ((const float4*)priors)[p];
            float gx = ((b0 + b2) * 0.5f - pr.x) / (pr.z * 0.1f);
            float gy = ((b1 + b3) * 0.5f - pr.y) / (pr.w * 0.1f);
            float gw = logf((b2 - b0) / pr.z) * 5.0f;
            float gh = logf((b3 - b1) / pr.w) * 5.0f;
            float4 pl = ((const float4*)pred_locs)[b * PP + p];
            lsum += fabsf(pl.x - gx) + fabsf(pl.y - gy) + fabsf(pl.z - gw) + fabsf(pl.w - gh);
        }
    }
    for (int off = 32; off > 0; off >>= 1) {
        lsum += __shfl_down(lsum, off, 64);
        lpos += __shfl_down(lpos, off, 64);
    }
    if ((tid & 63) == 0) { sredf[tid >> 6] = lsum; sredi[tid >> 6] = lpos; }
    __syncthreads();
    if (tid == 0) {
        float s = 0.0f; int n = 0;
#pragma unroll
        for (int w = 0; w < 4; ++w) { s += sredf[w]; n += sredi[w]; }
        lsum_bs[b * NSL_C + sl] = s;
        npos_bs[b * NSL_C + sl] = n;
    }
}

// ---------------- kernel 3: streaming cross entropy ----------------
// grid NCE=8732 x 256: 4 lanes per prior, 64 priors/block. No LDS staging, no
// barrier in the hot path -> max occupancy; loads of prior k+1 overlap exp of k.
// Scalar dword loads (324 B prior stride breaks 16B alignment for vector loads).
__global__ __launch_bounds__(256) void ce_kernel(
    const float* __restrict__ scores, const signed char* __restrict__ lab,
    float* __restrict__ ce_neg, float* __restrict__ cepos)
{
    const int tid = threadIdx.x;
    const int g = tid >> 2, j = tid & 3;           // 4-lane group per prior
    const int bp = blockIdx.x * 64 + g;            // flat (b,p), exact cover
    const float* __restrict__ v = scores + (long long)bp * CC;
    const int l = (int)lab[bp];

    // lane j owns chunks c = 4k+j (classes 4c..4c+3), k=0..4; class 80 on lane 0
    float d[21];
#pragma unroll
    for (int k = 0; k < 5; ++k) {
        const int c4 = (4 * k + j) * 4;
#pragma unroll
        for (int q = 0; q < 4; ++q) d[4*k+q] = v[c4 + q];
    }
    d[20] = (j == 0) ? v[80] : -3.0e38f;

    float m = d[20];
#pragma unroll
    for (int i = 0; i < 20; ++i) m = fmaxf(m, d[i]);
    m = fmaxf(m, __shfl_xor(m, 1, 64));
    m = fmaxf(m, __shfl_xor(m, 2, 64));

    float s = 0.0f;
#pragma unroll
    for (int i = 0; i < 21; ++i) s += __expf(d[i] - m);   // j!=0: d[20] underflows to 0

    float vl = 0.0f;                               // score at the label class
    if (l == 80) { if (j == 0) vl = d[20]; }
    else { int c = l >> 2; if ((c & 3) == j) vl = d[4 * (c >> 2) + (l & 3)]; }

    s  += __shfl_xor(s, 1, 64);   s  += __shfl_xor(s, 2, 64);
    vl += __shfl_xor(vl, 1, 64);  vl += __shfl_xor(vl, 2, 64);

    float ce = m + __logf(s) - vl;
    if (j == 0) ce_neg[bp] = (l != 0) ? 0.0f : ce;
    float posc = (l != 0 && j == 0) ? ce : 0.0f;

    for (int off = 32; off > 0; off >>= 1) posc += __shfl_down(posc, off, 64);
    __shared__ float sr[4];
    if ((tid & 63) == 0) sr[tid >> 6] = posc;
    __syncthreads();
    if (tid == 0) cepos[blockIdx.x] = sr[0] + sr[1] + sr[2] + sr[3];
}

// ---------------- kernel 4: per-batch exact top-K radix select + fused finalize ------
// grid B x 512. Parallel suffix-scan bin selection; last block writes out[0].
__global__ __launch_bounds__(512) void topk_kernel(
    const float* __restrict__ ce_neg, const int* __restrict__ npos_bs,
    const float* __restrict__ cepos, const float* __restrict__ lsum_bs,
    float* __restrict__ hard_b, int* __restrict__ done, float* __restrict__ out)
{
    __shared__ float sv[PP];          // 34928 B
    __shared__ int hist[256 * 16];    // 16-way slot-split histogram (16 KB)
    __shared__ int ssum[256];
    __shared__ unsigned sel[2];
    __shared__ float sr[8];
    __shared__ int sK;
    const int b = blockIdx.x, tid = threadIdx.x;
    for (int p = tid; p < PP; p += 512) sv[p] = ce_neg[b * PP + p];
    if (tid == 0) {
        int n = 0;
        for (int c = 0; c < NSL_C; ++c) n += npos_bs[b * NSL_C + c];
        int k = NEGPOS * n;
        sK = (k > PP) ? PP : k;
    }
    __syncthreads();
    const int K = sK;

    float hard = 0.0f;
    if (K > 0) {
        unsigned prefix = 0, mask = 0;
        unsigned remaining = (unsigned)K;
        for (int pass = 0; pass < 4; ++pass) {
            const int shift = 24 - 8 * pass;
            for (int i = tid; i < 256 * 16; i += 512) hist[i] = 0;
            __syncthreads();
            for (int p = tid; p < PP; p += 512) {
                unsigned u = __float_as_uint(sv[p]);   // all ce >= 0: bits monotone
                if ((u & mask) == prefix)
                    atomicAdd(&hist[(((u >> shift) & 255) << 4) | (tid & 15)], 1);
            }
            __syncthreads();
            if (tid < 256) {   // thread i compacts bin i
                int s = 0;
#pragma unroll
                for (int w = 0; w < 16; ++w) s += hist[(tid << 4) | w];
                ssum[tid] = s;
            }
            __syncthreads();
            // parallel suffix sum (Hillis-Steele): ssum[i] = sum_{j>=i} count[j]
            for (int off = 1; off < 256; off <<= 1) {
                int vv = 0;
                if (tid < 256) vv = (tid + off < 256) ? ssum[tid + off] : 0;
                __syncthreads();
                if (tid < 256) ssum[tid] += vv;
                __syncthreads();
            }
            if (tid < 256 && (unsigned)ssum[tid] >= remaining &&
                (tid == 255 || (unsigned)ssum[tid + 1] < remaining)) {
                sel[0] = (unsigned)tid;
                sel[1] = remaining - ((tid == 255) ? 0u : (unsigned)ssum[tid + 1]);
            }
            __syncthreads();
            prefix |= sel[0] << shift;
            mask |= 0xFFu << shift;
            remaining = sel[1];
            __syncthreads();
        }
        float sgt = 0.0f;
        for (int p = tid; p < PP; p += 512) {
            unsigned u = __float_as_uint(sv[p]);
            if (u > prefix) sgt += sv[p];
        }
        for (int off = 32; off > 0; off >>= 1) sgt += __shfl_down(sgt, off, 64);
        if ((tid & 63) == 0) sr[tid >> 6] = sgt;
        __syncthreads();
        if (tid == 0) {
            hard = 0.0f;
#pragma unroll
            for (int w = 0; w < 8; ++w) hard += sr[w];
            hard += __uint_as_float(prefix) * (float)remaining;
        }
    }
    __shared__ int sticket;
    if (tid == 0) {
        hard_b[b] = hard;
        __threadfence();                 // device-scope: flush before taking ticket
        sticket = atomicAdd(done, 1);
    }
    __syncthreads();
    if (sticket != BB - 1) return;

    // ---- fused finalize (last block only) ----
    float cpos = 0.0f, labs = 0.0f, chard = 0.0f; int n = 0;
    for (int i = tid; i < NCE; i += 512) cpos += cepos[i];
    for (int i = tid; i < BB * NSL_C; i += 512) { labs += lsum_bs[i]; n += npos_bs[i]; }
    if (tid < BB) chard = atomicAdd(&hard_b[tid], 0.0f);   // atomic load: XCD-coherent
    for (int off = 32; off > 0; off >>= 1) {
        cpos  += __shfl_down(cpos, off, 64);
        labs  += __shfl_down(labs, off, 64);
        chard += __shfl_down(chard, off, 64);
        n     += __shfl_down(n, off, 64);
    }
    __shared__ float f0[8], f1[8], f2[8];
    __shared__ int i3[8];
    if ((tid & 63) == 0) { int w = tid >> 6; f0[w] = cpos; f1[w] = labs; f2[w] = chard; i3[w] = n; }
    __syncthreads();
    if (tid == 0) {
        float a = 0.0f, bs = 0.0f, c = 0.0f; int nt = 0;
#pragma unroll
        for (int w = 0; w < 8; ++w) { a += f0[w]; bs += f1[w]; c += f2[w]; nt += i3[w]; }
        float nf = (float)nt;
        out[0] = (c + a) / nf + bs / (nf * 4.0f);
    }
}

extern "C" void kernel_launch(void* const* d_in, const int* in_sizes, int n_in,
                              void* d_out, int out_size, void* d_ws, size_t ws_size,
                              hipStream_t stream) {
    const float* pred_locs   = (const float*)d_in[0];   // [B,P,4]
    const float* pred_scores = (const float*)d_in[1];   // [B,P,C]
    const float* boxes       = (const float*)d_in[2];   // [B,O,4]
    const int*   labels      = (const int*)d_in[3];     // [B,O]
    const float* priors      = (const float*)d_in[4];   // [P,4] cxcywh
    float* out = (float*)d_out;

    char* ws = (char*)d_ws;
    float* povf = (float*)(ws + WS_POVF);
    unsigned char* povo = (unsigned char*)(ws + WS_POVO);
    unsigned long long* bestp = (unsigned long long*)(ws + WS_BESTP);
    signed char* lab = (signed char*)(ws + WS_LAB);
    float* ce_neg  = (float*)(ws + WS_CENEG);
    float* cepos   = (float*)(ws + WS_CEPOS);
    float* lsum_bs = (float*)(ws + WS_LSUMB);
    int*   nposbs  = (int*)(ws + WS_NPOSB);
    float* hard_b  = (float*)(ws + WS_HARDB);
    int*   done    = (int*)(ws + WS_DONE);

    match_geom<<<dim3(NSL_A + NCH_B, BB), 512, 0, stream>>>(boxes, priors, povf, povo, bestp, done);
    match_b<<<dim3(NSL_C, BB), 256, 0, stream>>>(pred_locs, boxes, labels, priors,
                                                 povf, povo, bestp, lab, nposbs, lsum_bs);
    ce_kernel<<<NCE, 256, 0, stream>>>(pred_scores, lab, ce_neg, cepos);
    topk_kernel<<<BB, 512, 0, stream>>>(ce_neg, nposbs, cepos, lsum_bs, hard_b, done, out);
}

// Round 7
// 318.823 us; speedup vs baseline: 1.1440x; 1.0079x over previous
//
#include <hip/hip_runtime.h>

#define BB 64
#define PP 8732
#define OO 32
#define CC 81
#define NEGPOS 3
#define NSL_A 18                   // per-prior part: 18*512 = 9216 >= 8732
#define NCH_B 32                   // per-object chunks: 32*273 = 8736 >= 8732
#define CHB 273
#define NCEB 137                   // ce blocks per batch: 137*64 = 8768 >= 8732

// ---------------- workspace layout (poison-proof: every word written before read) ----
#define WS_POVF   0                              // f32 povf[B*PP]  best iou per prior
#define WS_POVO   (WS_POVF  + BB*PP*4)           // u8  povo[B*PP]  best obj per prior
#define WS_BESTP  (WS_POVO  + BB*PP)             // u64 bestp[B*NCH_B*OO]
#define WS_CENEG  (WS_BESTP + BB*NCH_B*OO*8)     // f32 ce_neg[B*PP]
#define WS_CEPOS  (WS_CENEG + BB*PP*4)           // f32 cepos[B*NCEB]
#define WS_LSUMB  (WS_CEPOS + BB*NCEB*4)         // f32 lsum_bc[B*NCEB]
#define WS_NPOSB  (WS_LSUMB + BB*NCEB*4)         // i32 npos_bc[B*NCEB]
#define WS_HARDB  (WS_NPOSB + BB*NCEB*4)         // f32 hard_b[B]
#define WS_DONE   (WS_HARDB + BB*4)              // int done

// ---------------- kernel 1: fused geometry (per-prior argmax + per-object argmax) ----
// grid (NSL_A + NCH_B, B) x 512. blockIdx.x < NSL_A -> per-prior; else per-object chunk.
__global__ __launch_bounds__(512) void match_geom(
    const float* __restrict__ boxes, const float* __restrict__ priors,
    float* __restrict__ povf, unsigned char* __restrict__ povo,
    unsigned long long* __restrict__ bestp, int* __restrict__ done)
{
    const int b = blockIdx.y, gx = blockIdx.x, tid = threadIdx.x;
    __shared__ float sbx[OO * 4];
    __shared__ unsigned long long sred[8 * OO];
    if (tid < OO * 4) sbx[tid] = boxes[b * OO * 4 + tid];
    if (gx == 0 && b == 0 && tid == 0) *done = 0;   // ticket for topk's fused finalize
    __syncthreads();

    if (gx < NSL_A) {
        const int p = gx * 512 + tid;
        if (p >= PP) return;
        float4 pr = ((const float4*)priors)[p];
        float plx = pr.x - pr.z * 0.5f, ply = pr.y - pr.w * 0.5f;
        float phx = pr.x + pr.z * 0.5f, phy = pr.y + pr.w * 0.5f;
        float parea = pr.z * pr.w;
        float bestv = -1.0f; int besto = 0;
#pragma unroll
        for (int o = 0; o < OO; ++o) {
            float b0 = sbx[o*4+0], b1 = sbx[o*4+1], b2 = sbx[o*4+2], b3 = sbx[o*4+3];
            float lox = fmaxf(b0, plx), loy = fmaxf(b1, ply);
            float hix = fminf(b2, phx), hiy = fminf(b3, phy);
            float inter = fmaxf(hix - lox, 0.0f) * fmaxf(hiy - loy, 0.0f);
            float iou = inter / ((b2 - b0) * (b3 - b1) + parea - inter);
            if (iou > bestv) { bestv = iou; besto = o; }   // strict >: np first-max
        }
        povf[b * PP + p] = bestv;
        povo[b * PP + p] = (unsigned char)besto;
    } else {
        const int ch = gx - NSL_A;
        const int o = tid & 31, sub = tid >> 5;            // sub 0..15
        const float b0 = sbx[o*4+0], b1 = sbx[o*4+1], b2 = sbx[o*4+2], b3 = sbx[o*4+3];
        const float barea = (b2 - b0) * (b3 - b1);
        const int base = ch * CHB;
        unsigned long long best = 0ull;
        for (int i = sub; i < CHB; i += 16) {
            int p = base + i;
            if (p >= PP) break;
            float4 pr = ((const float4*)priors)[p];
            float plx = pr.x - pr.z * 0.5f, ply = pr.y - pr.w * 0.5f;
            float phx = pr.x + pr.z * 0.5f, phy = pr.y + pr.w * 0.5f;
            float parea = pr.z * pr.w;
            float lox = fmaxf(b0, plx), loy = fmaxf(b1, ply);
            float hix = fminf(b2, phx), hiy = fminf(b3, phy);
            float inter = fmaxf(hix - lox, 0.0f) * fmaxf(hiy - loy, 0.0f);
            float iou = inter / (barea + parea - inter);
            unsigned long long enc =
                ((unsigned long long)__float_as_uint(iou) << 32) | (unsigned)(~(unsigned)p);
            best = (enc > best) ? enc : best;              // max iou, tie -> min p
        }
        unsigned long long w = __shfl_down(best, 32, 64);  // lanes l / l+32 share object
        best = (w > best) ? w : best;
        const int wid = tid >> 6, lane = tid & 63;
        if (lane < 32) sred[wid * OO + o] = best;
        __syncthreads();
        if (tid < OO) {
            unsigned long long m = 0ull;
#pragma unroll
            for (int wv = 0; wv < 8; ++wv) {
                unsigned long long v = sred[wv * OO + tid];
                m = (v > m) ? v : m;
            }
            bestp[(b * NCH_B + ch) * OO + tid] = m;
        }
    }
}

// ---------------- kernel 2: fused streaming CE + labels + loc loss ----------------
// grid (NCEB, B) x 256: 4 lanes/prior, 64 priors/block. ~1.3 KB LDS, one barrier,
// full occupancy. Match-override via 32-iter LDS-broadcast scan (last-write-wins).
__global__ __launch_bounds__(256) void ce_match(
    const float* __restrict__ scores, const float* __restrict__ pred_locs,
    const float* __restrict__ boxes, const int* __restrict__ labels,
    const float* __restrict__ priors,
    const float* __restrict__ povf, const unsigned char* __restrict__ povo,
    const unsigned long long* __restrict__ bestp,
    float* __restrict__ ce_neg, float* __restrict__ cepos,
    float* __restrict__ lsum_bc, int* __restrict__ npos_bc)
{
    const int b = blockIdx.y, ch = blockIdx.x, tid = threadIdx.x;
    const int base = ch * 64;
    __shared__ float sbx[OO * 4];
    __shared__ int   slab[OO];
    __shared__ int   spfo[OO];
    __shared__ float srf[4], srl[4];
    __shared__ int   sri[4];

    if (tid < OO * 4) sbx[tid] = boxes[b * OO * 4 + tid];
    if (tid >= 224)   slab[tid - 224] = labels[b * OO + (tid - 224)];
    if (tid < OO) {    // reduce chunk-partials -> prior_for_object (8 KB, L2-hot)
        unsigned long long m = 0ull;
#pragma unroll 4
        for (int c = 0; c < NCH_B; ++c) {
            unsigned long long v = bestp[(b * NCH_B + c) * OO + tid];
            m = (v > m) ? v : m;
        }
        spfo[tid] = (int)(~(unsigned)(m & 0xFFFFFFFFull));
    }
    __syncthreads();

    const int g = tid >> 2, j = tid & 3;           // 4-lane group per prior
    const int p = base + g;
    float posc = 0.0f, lsum = 0.0f; int lpos = 0;

    if (p < PP) {
        const long long bp = (long long)b * PP + p;
        const float* __restrict__ v = scores + bp * CC;

        // lane j owns chunks c = 4k+j (classes 4c..4c+3), k=0..4; class 80 on lane 0
        float d[21];
#pragma unroll
        for (int k = 0; k < 5; ++k) {
            const int c4 = (4 * k + j) * 4;
#pragma unroll
            for (int q = 0; q < 4; ++q) d[4*k+q] = v[c4 + q];
        }
        d[20] = (j == 0) ? v[80] : -3.0e38f;

        // label with forced-positive override (ascending o => last-write-wins)
        int o = (int)povo[bp];
        float ov = povf[bp];
#pragma unroll
        for (int oo = 0; oo < OO; ++oo)
            if (spfo[oo] == p) { o = oo; ov = 1.0f; }    // LDS broadcast, free
        const int l = (ov < 0.5f) ? 0 : slab[o];

        float m = d[20];
#pragma unroll
        for (int i = 0; i < 20; ++i) m = fmaxf(m, d[i]);
        m = fmaxf(m, __shfl_xor(m, 1, 64));
        m = fmaxf(m, __shfl_xor(m, 2, 64));

        float s = 0.0f;
#pragma unroll
        for (int i = 0; i < 21; ++i) s += __expf(d[i] - m);  // j!=0: d[20] underflows to 0

        float vl = 0.0f;                           // score at the label class
        if (l == 80) { if (j == 0) vl = d[20]; }
        else { int c = l >> 2; if ((c & 3) == j) vl = d[4 * (c >> 2) + (l & 3)]; }

        s  += __shfl_xor(s, 1, 64);   s  += __shfl_xor(s, 2, 64);
        vl += __shfl_xor(vl, 1, 64);  vl += __shfl_xor(vl, 2, 64);

        float ce = m + __logf(s) - vl;
        if (j == 0) {
            ce_neg[bp] = (l != 0) ? 0.0f : ce;
            if (l != 0) {
                posc = ce; lpos = 1;
                float b0 = sbx[o*4+0], b1 = sbx[o*4+1], b2 = sbx[o*4+2], b3 = sbx[o*4+3];
                float4 pr = ((const float4*)priors)[p];
                float gx = ((b0 + b2) * 0.5f - pr.x) / (pr.z * 0.1f);
                float gy = ((b1 + b3) * 0.5f - pr.y) / (pr.w * 0.1f);
                float gw = logf((b2 - b0) / pr.z) * 5.0f;
                float gh = logf((b3 - b1) / pr.w) * 5.0f;
                float4 pl = ((const float4*)pred_locs)[bp];
                lsum = fabsf(pl.x - gx) + fabsf(pl.y - gy)
                     + fabsf(pl.z - gw) + fabsf(pl.w - gh);
            }
        }
    }

    for (int off = 32; off > 0; off >>= 1) {
        posc += __shfl_down(posc, off, 64);
        lsum += __shfl_down(lsum, off, 64);
        lpos += __shfl_down(lpos, off, 64);
    }
    if ((tid & 63) == 0) { int w = tid >> 6; srf[w] = posc; srl[w] = lsum; sri[w] = lpos; }
    __syncthreads();
    if (tid == 0) {
        cepos[b * NCEB + ch]   = srf[0] + srf[1] + srf[2] + srf[3];
        lsum_bc[b * NCEB + ch] = srl[0] + srl[1] + srl[2] + srl[3];
        npos_bc[b * NCEB + ch] = sri[0] + sri[1] + sri[2] + sri[3];
    }
}

// ---------------- kernel 3: per-batch exact top-K radix select + fused finalize ------
// grid B x 512. Parallel suffix-scan bin selection; last block writes out[0].
__global__ __launch_bounds__(512) void topk_kernel(
    const float* __restrict__ ce_neg, const int* __restrict__ npos_bc,
    const float* __restrict__ cepos, const float* __restrict__ lsum_bc,
    float* __restrict__ hard_b, int* __restrict__ done, float* __restrict__ out)
{
    __shared__ float sv[PP];          // 34928 B
    __shared__ int hist[256 * 16];    // 16-way slot-split histogram (16 KB)
    __shared__ int ssum[256];
    __shared__ unsigned sel[2];
    __shared__ float sr[8];
    __shared__ int sKred[8];
    const int b = blockIdx.x, tid = threadIdx.x;
    for (int p = tid; p < PP; p += 512) sv[p] = ce_neg[b * PP + p];

    // parallel K reduce over NCEB partials
    {
        int n = 0;
        for (int c = tid; c < NCEB; c += 512) n += npos_bc[b * NCEB + c];
        for (int off = 32; off > 0; off >>= 1) n += __shfl_down(n, off, 64);
        if ((tid & 63) == 0) sKred[tid >> 6] = n;
    }
    __syncthreads();
    int K;
    {
        int n = 0;
#pragma unroll
        for (int w = 0; w < 8; ++w) n += sKred[w];
        K = NEGPOS * n;
        if (K > PP) K = PP;
    }

    float hard = 0.0f;
    if (K > 0) {
        unsigned prefix = 0, mask = 0;
        unsigned remaining = (unsigned)K;
        for (int pass = 0; pass < 4; ++pass) {
            const int shift = 24 - 8 * pass;
            for (int i = tid; i < 256 * 16; i += 512) hist[i] = 0;
            __syncthreads();
            for (int p = tid; p < PP; p += 512) {
                unsigned u = __float_as_uint(sv[p]);   // all ce >= 0: bits monotone
                if ((u & mask) == prefix)
                    atomicAdd(&hist[(((u >> shift) & 255) << 4) | (tid & 15)], 1);
            }
            __syncthreads();
            if (tid < 256) {   // thread i compacts bin i
                int s = 0;
#pragma unroll
                for (int w = 0; w < 16; ++w) s += hist[(tid << 4) | w];
                ssum[tid] = s;
            }
            __syncthreads();
            // parallel suffix sum (Hillis-Steele): ssum[i] = sum_{j>=i} count[j]
            for (int off = 1; off < 256; off <<= 1) {
                int vv = 0;
                if (tid < 256) vv = (tid + off < 256) ? ssum[tid + off] : 0;
                __syncthreads();
                if (tid < 256) ssum[tid] += vv;
                __syncthreads();
            }
            if (tid < 256 && (unsigned)ssum[tid] >= remaining &&
                (tid == 255 || (unsigned)ssum[tid + 1] < remaining)) {
                sel[0] = (unsigned)tid;
                sel[1] = remaining - ((tid == 255) ? 0u : (unsigned)ssum[tid + 1]);
            }
            __syncthreads();
            prefix |= sel[0] << shift;
            mask |= 0xFFu << shift;
            remaining = sel[1];
            __syncthreads();
        }
        float sgt = 0.0f;
        for (int p = tid; p < PP; p += 512) {
            unsigned u = __float_as_uint(sv[p]);
            if (u > prefix) sgt += sv[p];
        }
        for (int off = 32; off > 0; off >>= 1) sgt += __shfl_down(sgt, off, 64);
        if ((tid & 63) == 0) sr[tid >> 6] = sgt;
        __syncthreads();
        if (tid == 0) {
            hard = 0.0f;
#pragma unroll
            for (int w = 0; w < 8; ++w) hard += sr[w];
            hard += __uint_as_float(prefix) * (float)remaining;
        }
    }
    __shared__ int sticket;
    if (tid == 0) {
        hard_b[b] = hard;
        __threadfence();                 // device-scope: flush before taking ticket
        sticket = atomicAdd(done, 1);
    }
    __syncthreads();
    if (sticket != BB - 1) return;

    // ---- fused finalize (last block only) ----
    float cpos = 0.0f, labs = 0.0f, chard = 0.0f; int n = 0;
    for (int i = tid; i < BB * NCEB; i += 512) {
        cpos += cepos[i];                 // prior-launch outputs: visible at launch edge
        labs += lsum_bc[i];
        n    += npos_bc[i];
    }
    if (tid < BB) chard = atomicAdd(&hard_b[tid], 0.0f);   // atomic load: XCD-coherent
    for (int off = 32; off > 0; off >>= 1) {
        cpos  += __shfl_down(cpos, off, 64);
        labs  += __shfl_down(labs, off, 64);
        chard += __shfl_down(chard, off, 64);
        n     += __shfl_down(n, off, 64);
    }
    __shared__ float f0[8], f1[8], f2[8];
    __shared__ int i3[8];
    if ((tid & 63) == 0) { int w = tid >> 6; f0[w] = cpos; f1[w] = labs; f2[w] = chard; i3[w] = n; }
    __syncthreads();
    if (tid == 0) {
        float a = 0.0f, bs = 0.0f, c = 0.0f; int nt = 0;
#pragma unroll
        for (int w = 0; w < 8; ++w) { a += f0[w]; bs += f1[w]; c += f2[w]; nt += i3[w]; }
        float nf = (float)nt;
        out[0] = (c + a) / nf + bs / (nf * 4.0f);
    }
}

extern "C" void kernel_launch(void* const* d_in, const int* in_sizes, int n_in,
                              void* d_out, int out_size, void* d_ws, size_t ws_size,
                              hipStream_t stream) {
    const float* pred_locs   = (const float*)d_in[0];   // [B,P,4]
    const float* pred_scores = (const float*)d_in[1];   // [B,P,C]
    const float* boxes       = (const float*)d_in[2];   // [B,O,4]
    const int*   labels      = (const int*)d_in[3];     // [B,O]
    const float* priors      = (const float*)d_in[4];   // [P,4] cxcywh
    float* out = (float*)d_out;

    char* ws = (char*)d_ws;
    float* povf = (float*)(ws + WS_POVF);
    unsigned char* povo = (unsigned char*)(ws + WS_POVO);
    unsigned long long* bestp = (unsigned long long*)(ws + WS_BESTP);
    float* ce_neg  = (float*)(ws + WS_CENEG);
    float* cepos   = (float*)(ws + WS_CEPOS);
    float* lsum_bc = (float*)(ws + WS_LSUMB);
    int*   nposbc  = (int*)(ws + WS_NPOSB);
    float* hard_b  = (float*)(ws + WS_HARDB);
    int*   done    = (int*)(ws + WS_DONE);

    match_geom<<<dim3(NSL_A + NCH_B, BB), 512, 0, stream>>>(boxes, priors, povf, povo, bestp, done);
    ce_match<<<dim3(NCEB, BB), 256, 0, stream>>>(pred_scores, pred_locs, boxes, labels,
                                                 priors, povf, povo, bestp,
                                                 ce_neg, cepos, lsum_bc, nposbc);
    topk_kernel<<<BB, 512, 0, stream>>>(ce_neg, nposbc, cepos, lsum_bc, hard_b, done, out);
}